// Round 1
// baseline (127.841 us; speedup 1.0000x reference)
//
#include <hip/hip_runtime.h>
#include <math.h>

// Problem constants (from reference): Q=4096 queries, N=50000 refs, D=5, L=2
#define QTOT 4096
#define NTOT 50000
#define CHUNK 512   // n-chunk per block; LDS = CHUNK*8 floats = 16 KB

#if __has_builtin(__builtin_amdgcn_exp2f)
#define EXP2F(x) __builtin_amdgcn_exp2f(x)
#else
#define EXP2F(x) exp2f(x)
#endif

// Main: grid.x = Q/256 q-blocks, grid.y = ceil(N/CHUNK) chunks.
// lane = query; inner loop over chunk n's via uniform (broadcast) LDS reads.
// sim = exp(-d2/(2s^2)) = 2^t,  t = 2g*dot(x,r) - g*|x|^2 - g*|r|^2,
// g = log2(e)/(2 s^2).  Clamp d2>=0  <=>  t = min(t, 0).
__global__ __launch_bounds__(256) void sknn_main(
    const float* __restrict__ rss,   // [Q,5]
    const float* __restrict__ Radio, // [N,5]
    const float* __restrict__ Loc,   // [N,2]
    const float* __restrict__ sigma, // [1]
    float* __restrict__ acc)         // [3*Q]: sum | acc_l0 | acc_l1
{
    __shared__ float P[CHUNK * 8];   // per-n: {2g*r0..r4, -g*|r|^2, l0, l1}

    const int tid = threadIdx.x;
    const int qb  = blockIdx.x;
    const int n0  = blockIdx.y * CHUNK;
    const int cn  = min(n0 + CHUNK, NTOT) - n0;

    const float sg = sigma[0];
    const float g  = 1.4426950408889634f / (2.0f * sg * sg); // log2e/(2s^2)
    const float g2 = 2.0f * g;

    // Stage + transform this chunk into LDS (once per block; trivial cost).
    for (int i = tid; i < cn; i += 256) {
        const int n = n0 + i;
        const float r0 = Radio[n * 5 + 0];
        const float r1 = Radio[n * 5 + 1];
        const float r2 = Radio[n * 5 + 2];
        const float r3 = Radio[n * 5 + 3];
        const float r4 = Radio[n * 5 + 4];
        const float rr = r0 * r0 + r1 * r1 + r2 * r2 + r3 * r3 + r4 * r4;
        float4* p4 = (float4*)&P[i * 8];
        p4[0] = make_float4(g2 * r0, g2 * r1, g2 * r2, g2 * r3);
        p4[1] = make_float4(g2 * r4, -g * rr, Loc[n * 2 + 0], Loc[n * 2 + 1]);
    }
    __syncthreads();

    const int q = qb * 256 + tid;    // Q = 4096 = gridDim.x*256 exactly
    const float x0 = rss[q * 5 + 0];
    const float x1 = rss[q * 5 + 1];
    const float x2 = rss[q * 5 + 2];
    const float x3 = rss[q * 5 + 3];
    const float x4 = rss[q * 5 + 4];
    const float aq = -g * (x0 * x0 + x1 * x1 + x2 * x2 + x3 * x3 + x4 * x4);

    float s_sum = 0.0f, a0 = 0.0f, a1 = 0.0f;
    const float4* p4 = (const float4*)P;
    #pragma unroll 4
    for (int i = 0; i < cn; ++i) {
        const float4 f0 = p4[2 * i];      // uniform address -> LDS broadcast
        const float4 f1 = p4[2 * i + 1];
        float t = fmaf(x0, f0.x, aq);
        t = fmaf(x1, f0.y, t);
        t = fmaf(x2, f0.z, t);
        t = fmaf(x3, f0.w, t);
        t = fmaf(x4, f1.x, t);
        t += f1.y;
        t = fminf(t, 0.0f);               // d2 >= 0 clamp
        const float s = EXP2F(t);
        s_sum += s;
        a0 = fmaf(s, f1.z, a0);
        a1 = fmaf(s, f1.w, a1);
    }

    // ~98 contenders per address total — negligible.
    atomicAdd(&acc[q],            s_sum);
    atomicAdd(&acc[QTOT + q],     a0);
    atomicAdd(&acc[2 * QTOT + q], a1);
}

__global__ __launch_bounds__(256) void sknn_fin(
    const float* __restrict__ acc, float* __restrict__ out)
{
    const int q = blockIdx.x * 256 + threadIdx.x;
    if (q < QTOT) {
        const float inv = 1.0f / acc[q];
        out[q * 2 + 0] = acc[QTOT + q] * inv;
        out[q * 2 + 1] = acc[2 * QTOT + q] * inv;
    }
}

extern "C" void kernel_launch(void* const* d_in, const int* in_sizes, int n_in,
                              void* d_out, int out_size, void* d_ws, size_t ws_size,
                              hipStream_t stream) {
    const float* rss   = (const float*)d_in[0]; // [4096,5]
    const float* Radio = (const float*)d_in[1]; // [50000,5]
    const float* Loc   = (const float*)d_in[2]; // [50000,2]
    const float* sigma = (const float*)d_in[3]; // [1]
    float* out = (float*)d_out;                 // [4096,2] fp32
    float* acc = (float*)d_ws;                  // 3*Q floats = 48 KB

    hipMemsetAsync(acc, 0, 3 * QTOT * sizeof(float), stream);

    dim3 grid(QTOT / 256, (NTOT + CHUNK - 1) / CHUNK);
    sknn_main<<<grid, dim3(256), 0, stream>>>(rss, Radio, Loc, sigma, acc);
    sknn_fin<<<QTOT / 256, dim3(256), 0, stream>>>(acc, out);
}

// Round 2
// 124.941 us; speedup vs baseline: 1.0232x; 1.0232x over previous
//
#include <hip/hip_runtime.h>
#include <math.h>

// Q=4096 queries, N=50000 refs, D=5, L=2
#define QTOT 4096
#define NTOT 50000
#define CHUNK 512          // n's per block-chunk
#define NPAIR (CHUNK / 2)  // 256 pairs; == blockDim, so staging is 1 pair/thread

typedef float f2 __attribute__((ext_vector_type(2)));
typedef float f4 __attribute__((ext_vector_type(4)));

#if __has_builtin(__builtin_amdgcn_exp2f)
#define EXP2F(x) __builtin_amdgcn_exp2f(x)
#else
#define EXP2F(x) exp2f(x)
#endif

static __device__ __forceinline__ f2 fma2(f2 a, f2 b, f2 c) {
#if __has_builtin(__builtin_elementwise_fma)
    return __builtin_elementwise_fma(a, b, c);
#else
    f2 r; r.x = fmaf(a.x, b.x, c.x); r.y = fmaf(a.y, b.y, c.y); return r;
#endif
}
static __device__ __forceinline__ f2 min2(f2 a, f2 b) {
#if __has_builtin(__builtin_elementwise_min)
    return __builtin_elementwise_min(a, b);
#else
    f2 r; r.x = fminf(a.x, b.x); r.y = fminf(a.y, b.y); return r;
#endif
}

// sim = exp(-d2/(2s^2)) = 2^t, t = 2g*(x.r) - g|x|^2 - g|r|^2, g = log2e/(2s^2)
// LDS layout per n-pair (a,b), 4 x float4 (all inner-loop reads are
// wave-uniform broadcasts; packed operands land pre-interleaved):
//   P[4p+0] = {2g*r0a, 2g*r0b, 2g*r1a, 2g*r1b}
//   P[4p+1] = {2g*r2a, 2g*r2b, 2g*r3a, 2g*r3b}
//   P[4p+2] = {2g*r4a, 2g*r4b, -g|ra|^2, -g|rb|^2}
//   P[4p+3] = {l0a, l0b, l1a, l1b}
// Padded n (>=NTOT): r=0, nrr=-1e30, l=0  =>  s = 2^(-1e30) = 0 exactly.
__global__ __launch_bounds__(256) void sknn_main(
    const float* __restrict__ rss,   // [Q,5]
    const float* __restrict__ Radio, // [N,5]
    const float* __restrict__ Loc,   // [N,2]
    const float* __restrict__ sigma, // [1]
    float* __restrict__ acc)         // [3*Q]: sum | acc_l0 | acc_l1
{
    __shared__ f4 P[NPAIR * 4];      // 16 KB

    const int tid = threadIdx.x;
    const int n0  = blockIdx.y * CHUNK;

    const float sg = sigma[0];
    const float g  = 1.4426950408889634f / (2.0f * sg * sg);
    const float g2 = 2.0f * g;

    // ---- stage one pair per thread ----
    {
        const int na = n0 + 2 * tid;
        const int nb = na + 1;
        float r0a=0.f, r1a=0.f, r2a=0.f, r3a=0.f, r4a=0.f, nra=-1e30f, l0a=0.f, l1a=0.f;
        float r0b=0.f, r1b=0.f, r2b=0.f, r3b=0.f, r4b=0.f, nrb=-1e30f, l0b=0.f, l1b=0.f;
        if (na < NTOT) {
            r0a = Radio[na*5+0]; r1a = Radio[na*5+1]; r2a = Radio[na*5+2];
            r3a = Radio[na*5+3]; r4a = Radio[na*5+4];
            nra = -g * (r0a*r0a + r1a*r1a + r2a*r2a + r3a*r3a + r4a*r4a);
            l0a = Loc[na*2+0]; l1a = Loc[na*2+1];
        }
        if (nb < NTOT) {
            r0b = Radio[nb*5+0]; r1b = Radio[nb*5+1]; r2b = Radio[nb*5+2];
            r3b = Radio[nb*5+3]; r4b = Radio[nb*5+4];
            nrb = -g * (r0b*r0b + r1b*r1b + r2b*r2b + r3b*r3b + r4b*r4b);
            l0b = Loc[nb*2+0]; l1b = Loc[nb*2+1];
        }
        P[4*tid+0] = (f4){g2*r0a, g2*r0b, g2*r1a, g2*r1b};
        P[4*tid+1] = (f4){g2*r2a, g2*r2b, g2*r3a, g2*r3b};
        P[4*tid+2] = (f4){g2*r4a, g2*r4b, nra, nrb};
        P[4*tid+3] = (f4){l0a, l0b, l1a, l1b};
    }
    __syncthreads();

    // ---- lane = query; loop over 256 pairs (compile-time trip count) ----
    const int q = blockIdx.x * 256 + tid;   // Q == gridDim.x*256 exactly
    const float x0 = rss[q*5+0], x1 = rss[q*5+1], x2 = rss[q*5+2];
    const float x3 = rss[q*5+3], x4 = rss[q*5+4];
    const float aq = -g * (x0*x0 + x1*x1 + x2*x2 + x3*x3 + x4*x4);

    const f2 x0v = {x0, x0}, x1v = {x1, x1}, x2v = {x2, x2};
    const f2 x3v = {x3, x3}, x4v = {x4, x4}, aqv = {aq, aq};
    const f2 zero = {0.f, 0.f};

    f2 ss = zero, aa0 = zero, aa1 = zero;
    #pragma unroll 4
    for (int p = 0; p < NPAIR; ++p) {
        const f4 pA = P[4*p+0];          // uniform addr -> LDS broadcast
        const f4 pB = P[4*p+1];
        const f4 pC = P[4*p+2];
        const f4 pD = P[4*p+3];
        f2 t = pC.zw + aqv;              // v_pk_add_f32
        t = fma2(x0v, pA.xy, t);         // v_pk_fma_f32 x5
        t = fma2(x1v, pA.zw, t);
        t = fma2(x2v, pB.xy, t);
        t = fma2(x3v, pB.zw, t);
        t = fma2(x4v, pC.xy, t);
        t = min2(t, zero);               // d2 >= 0 clamp
        f2 s; s.x = EXP2F(t.x); s.y = EXP2F(t.y);
        ss += s;
        aa0 = fma2(s, pD.xy, aa0);
        aa1 = fma2(s, pD.zw, aa1);
    }

    atomicAdd(&acc[q],          ss.x + ss.y);
    atomicAdd(&acc[QTOT + q],   aa0.x + aa0.y);
    atomicAdd(&acc[2*QTOT + q], aa1.x + aa1.y);
}

__global__ __launch_bounds__(256) void sknn_fin(
    const float* __restrict__ acc, float* __restrict__ out)
{
    const int q = blockIdx.x * 256 + threadIdx.x;
    if (q < QTOT) {
        const float inv = 1.0f / acc[q];
        out[q*2+0] = acc[QTOT + q]   * inv;
        out[q*2+1] = acc[2*QTOT + q] * inv;
    }
}

extern "C" void kernel_launch(void* const* d_in, const int* in_sizes, int n_in,
                              void* d_out, int out_size, void* d_ws, size_t ws_size,
                              hipStream_t stream) {
    const float* rss   = (const float*)d_in[0];
    const float* Radio = (const float*)d_in[1];
    const float* Loc   = (const float*)d_in[2];
    const float* sigma = (const float*)d_in[3];
    float* out = (float*)d_out;
    float* acc = (float*)d_ws;      // 3*Q floats = 48 KB

    hipMemsetAsync(acc, 0, 3 * QTOT * sizeof(float), stream);

    dim3 grid(QTOT / 256, (NTOT + CHUNK - 1) / CHUNK);
    sknn_main<<<grid, dim3(256), 0, stream>>>(rss, Radio, Loc, sigma, acc);
    sknn_fin<<<QTOT / 256, dim3(256), 0, stream>>>(acc, out);
}

// Round 3
// 122.242 us; speedup vs baseline: 1.0458x; 1.0221x over previous
//
#include <hip/hip_runtime.h>
#include <math.h>

// Q=4096 queries, N=50000 refs, D=5, L=2
#define QTOT  4096
#define NTOT  50000
#define CHUNK 512             // n's per block-chunk
#define NCHUNKS 98            // ceil(50000/512)
#define NPAD  (CHUNK * NCHUNKS)   // 50176
#define PAIRS_PER_CHUNK (CHUNK / 2)   // 256
#define NPAIRS (NPAD / 2)     // 25088
#define ACCN (3 * QTOT)       // 12288 floats of accumulators

typedef float f2 __attribute__((ext_vector_type(2)));
typedef float f4 __attribute__((ext_vector_type(4)));

#if __has_builtin(__builtin_amdgcn_exp2f)
#define EXP2F(x) __builtin_amdgcn_exp2f(x)
#else
#define EXP2F(x) exp2f(x)
#endif

static __device__ __forceinline__ f2 fma2(f2 a, f2 b, f2 c) {
#if __has_builtin(__builtin_elementwise_fma)
    return __builtin_elementwise_fma(a, b, c);
#else
    f2 r; r.x = fmaf(a.x, b.x, c.x); r.y = fmaf(a.y, b.y, c.y); return r;
#endif
}

// ---------------------------------------------------------------------------
// Prep: transform (Radio, Loc) -> Pg[pair][4 x f4] in d_ws, and zero acc.
// Per pair (a,b):
//   Pg[4p+0] = {2g*r0a, 2g*r0b, 2g*r1a, 2g*r1b}
//   Pg[4p+1] = {2g*r2a, 2g*r2b, 2g*r3a, 2g*r3b}
//   Pg[4p+2] = {2g*r4a, 2g*r4b, -g|ra|^2, -g|rb|^2}
//   Pg[4p+3] = {l0a, l0b, l1a, l1b}
// Padded n (>= NTOT): r=0, l=0, -g|r|^2 = -1e30  =>  2^t = 0 exactly.
// ---------------------------------------------------------------------------
__global__ __launch_bounds__(256) void sknn_prep(
    const float* __restrict__ Radio, const float* __restrict__ Loc,
    const float* __restrict__ sigma, f4* __restrict__ Pg,
    float* __restrict__ acc)
{
    const int p = blockIdx.x * 256 + threadIdx.x;   // pair id, exactly NPAIRS
    const float sg = sigma[0];
    const float g  = 1.4426950408889634f / (2.0f * sg * sg); // log2e/(2s^2)
    const float g2 = 2.0f * g;

    const int na = 2 * p, nb = 2 * p + 1;
    float r0a=0.f,r1a=0.f,r2a=0.f,r3a=0.f,r4a=0.f,nra=-1e30f,l0a=0.f,l1a=0.f;
    float r0b=0.f,r1b=0.f,r2b=0.f,r3b=0.f,r4b=0.f,nrb=-1e30f,l0b=0.f,l1b=0.f;
    if (na < NTOT) {
        r0a=Radio[na*5+0]; r1a=Radio[na*5+1]; r2a=Radio[na*5+2];
        r3a=Radio[na*5+3]; r4a=Radio[na*5+4];
        nra = -g*(r0a*r0a + r1a*r1a + r2a*r2a + r3a*r3a + r4a*r4a);
        l0a=Loc[na*2+0]; l1a=Loc[na*2+1];
    }
    if (nb < NTOT) {
        r0b=Radio[nb*5+0]; r1b=Radio[nb*5+1]; r2b=Radio[nb*5+2];
        r3b=Radio[nb*5+3]; r4b=Radio[nb*5+4];
        nrb = -g*(r0b*r0b + r1b*r1b + r2b*r2b + r3b*r3b + r4b*r4b);
        l0b=Loc[nb*2+0]; l1b=Loc[nb*2+1];
    }
    Pg[4*p+0] = (f4){g2*r0a, g2*r0b, g2*r1a, g2*r1b};
    Pg[4*p+1] = (f4){g2*r2a, g2*r2b, g2*r3a, g2*r3b};
    Pg[4*p+2] = (f4){g2*r4a, g2*r4b, nra, nrb};
    Pg[4*p+3] = (f4){l0a, l0b, l1a, l1b};

    // zero the 3*Q accumulators (first 48 blocks cover it)
    if (p < ACCN) acc[p] = 0.0f;
}

// ---------------------------------------------------------------------------
// Main: lane = query. All Pg reads are wave-uniform -> scalar (s_load) pipe.
// sim = 2^t, t = 2g*(x.r) - g|x|^2 - g|r|^2, clamped t<=0.
// ---------------------------------------------------------------------------
__global__ __launch_bounds__(256) void sknn_main(
    const float* __restrict__ rss, const float* __restrict__ sigma,
    const f4* __restrict__ Pg, float* __restrict__ acc)
{
    const int tid = threadIdx.x;
    const int q   = blockIdx.x * 256 + tid;     // gridDim.x = 16
    const float sg = sigma[0];
    const float g  = 1.4426950408889634f / (2.0f * sg * sg);

    const float x0 = rss[q*5+0], x1 = rss[q*5+1], x2 = rss[q*5+2];
    const float x3 = rss[q*5+3], x4 = rss[q*5+4];
    const float aq = -g*(x0*x0 + x1*x1 + x2*x2 + x3*x3 + x4*x4);

    const f2 x0v = {x0,x0}, x1v = {x1,x1}, x2v = {x2,x2};
    const f2 x3v = {x3,x3}, x4v = {x4,x4}, aqv = {aq,aq};
    const f2 zero = {0.f,0.f};

    // wave-uniform base for this chunk's 256 pairs
    const f4* __restrict__ Pp = Pg + 4 * (size_t)(blockIdx.y * PAIRS_PER_CHUNK);

    f2 ss = zero, aa0 = zero, aa1 = zero;
    #pragma unroll 4
    for (int p = 0; p < PAIRS_PER_CHUNK; ++p) {
        const f4 pA = Pp[4*p+0];    // uniform address -> s_load (scalar pipe)
        const f4 pB = Pp[4*p+1];
        const f4 pC = Pp[4*p+2];
        const f4 pD = Pp[4*p+3];
        f2 t = pC.zw + aqv;
        t = fma2(x0v, pA.xy, t);
        t = fma2(x1v, pA.zw, t);
        t = fma2(x2v, pB.xy, t);
        t = fma2(x3v, pB.zw, t);
        t = fma2(x4v, pC.xy, t);
        t.x = fminf(t.x, 0.0f);     // d2 >= 0 clamp
        t.y = fminf(t.y, 0.0f);
        f2 s; s.x = EXP2F(t.x); s.y = EXP2F(t.y);
        ss += s;
        aa0 = fma2(s, pD.xy, aa0);
        aa1 = fma2(s, pD.zw, aa1);
    }

    atomicAdd(&acc[q],          ss.x + ss.y);
    atomicAdd(&acc[QTOT + q],   aa0.x + aa0.y);
    atomicAdd(&acc[2*QTOT + q], aa1.x + aa1.y);
}

__global__ __launch_bounds__(256) void sknn_fin(
    const float* __restrict__ acc, float* __restrict__ out)
{
    const int q = blockIdx.x * 256 + threadIdx.x;
    if (q < QTOT) {
        const float inv = 1.0f / acc[q];
        out[q*2+0] = acc[QTOT + q]   * inv;
        out[q*2+1] = acc[2*QTOT + q] * inv;
    }
}

extern "C" void kernel_launch(void* const* d_in, const int* in_sizes, int n_in,
                              void* d_out, int out_size, void* d_ws, size_t ws_size,
                              hipStream_t stream) {
    const float* rss   = (const float*)d_in[0];
    const float* Radio = (const float*)d_in[1];
    const float* Loc   = (const float*)d_in[2];
    const float* sigma = (const float*)d_in[3];
    float* out = (float*)d_out;

    // ws layout: [Pg: NPAIRS*4*f4 = 1.6 MB][acc: 48 KB]
    f4*    Pg  = (f4*)d_ws;
    float* acc = (float*)((char*)d_ws + (size_t)NPAIRS * 4 * sizeof(f4));

    sknn_prep<<<NPAIRS / 256, dim3(256), 0, stream>>>(Radio, Loc, sigma, Pg, acc);
    dim3 grid(QTOT / 256, NCHUNKS);
    sknn_main<<<grid, dim3(256), 0, stream>>>(rss, sigma, Pg, acc);
    sknn_fin<<<QTOT / 256, dim3(256), 0, stream>>>(acc, out);
}

// Round 4
// 115.042 us; speedup vs baseline: 1.1113x; 1.0626x over previous
//
#include <hip/hip_runtime.h>
#include <math.h>

// Q=4096 queries, N=50000 refs, D=5, L=2
#define QTOT   4096
#define NTOT   50000
#define NCHUNKS 96
#define PAIRS_PER_CHUNK 264          // 264*96 = 25344 pairs = 50688 n (padded)
#define NPAIRS (NCHUNKS * PAIRS_PER_CHUNK)
#define ACCN   (3 * QTOT)
#define QPT    2                     // queries per thread
#define QBLOCKS (QTOT / (256 * QPT)) // 8

typedef float f2 __attribute__((ext_vector_type(2)));
typedef float f4 __attribute__((ext_vector_type(4)));

#if __has_builtin(__builtin_amdgcn_exp2f)
#define EXP2F(x) __builtin_amdgcn_exp2f(x)
#else
#define EXP2F(x) exp2f(x)
#endif

static __device__ __forceinline__ f2 fma2(f2 a, f2 b, f2 c) {
#if __has_builtin(__builtin_elementwise_fma)
    return __builtin_elementwise_fma(a, b, c);
#else
    f2 r; r.x = fmaf(a.x, b.x, c.x); r.y = fmaf(a.y, b.y, c.y); return r;
#endif
}

// ---------------------------------------------------------------------------
// Prep: (Radio, Loc, sigma) -> Pg[pair][4 x f4] in d_ws; zero acc.
//   Pg[4p+0] = {2g*r0a, 2g*r0b, 2g*r1a, 2g*r1b}
//   Pg[4p+1] = {2g*r2a, 2g*r2b, 2g*r3a, 2g*r3b}
//   Pg[4p+2] = {2g*r4a, 2g*r4b, -g|ra|^2, -g|rb|^2}
//   Pg[4p+3] = {l0a, l0b, l1a, l1b}
// Padded n (>= NTOT): r=0, l=0, -g|r|^2 = -1e30  =>  2^t = 0 exactly, so no
// clamp needed and padded entries contribute nothing.
// ---------------------------------------------------------------------------
__global__ __launch_bounds__(256) void sknn_prep(
    const float* __restrict__ Radio, const float* __restrict__ Loc,
    const float* __restrict__ sigma, f4* __restrict__ Pg,
    float* __restrict__ acc)
{
    const int p = blockIdx.x * 256 + threadIdx.x;
    if (p >= NPAIRS) return;
    const float sg = sigma[0];
    const float g  = 1.4426950408889634f / (2.0f * sg * sg); // log2e/(2s^2)
    const float g2 = 2.0f * g;

    const int na = 2 * p, nb = 2 * p + 1;
    float r0a=0.f,r1a=0.f,r2a=0.f,r3a=0.f,r4a=0.f,nra=-1e30f,l0a=0.f,l1a=0.f;
    float r0b=0.f,r1b=0.f,r2b=0.f,r3b=0.f,r4b=0.f,nrb=-1e30f,l0b=0.f,l1b=0.f;
    if (na < NTOT) {
        r0a=Radio[na*5+0]; r1a=Radio[na*5+1]; r2a=Radio[na*5+2];
        r3a=Radio[na*5+3]; r4a=Radio[na*5+4];
        nra = -g*(r0a*r0a + r1a*r1a + r2a*r2a + r3a*r3a + r4a*r4a);
        l0a=Loc[na*2+0]; l1a=Loc[na*2+1];
    }
    if (nb < NTOT) {
        r0b=Radio[nb*5+0]; r1b=Radio[nb*5+1]; r2b=Radio[nb*5+2];
        r3b=Radio[nb*5+3]; r4b=Radio[nb*5+4];
        nrb = -g*(r0b*r0b + r1b*r1b + r2b*r2b + r3b*r3b + r4b*r4b);
        l0b=Loc[nb*2+0]; l1b=Loc[nb*2+1];
    }
    Pg[4*p+0] = (f4){g2*r0a, g2*r0b, g2*r1a, g2*r1b};
    Pg[4*p+1] = (f4){g2*r2a, g2*r2b, g2*r3a, g2*r3b};
    Pg[4*p+2] = (f4){g2*r4a, g2*r4b, nra, nrb};
    Pg[4*p+3] = (f4){l0a, l0b, l1a, l1b};

    if (p < ACCN) acc[p] = 0.0f;
}

// ---------------------------------------------------------------------------
// Main: each thread owns 2 queries (q0, q0+256); every wave-uniform 64 B Pg
// record (scalar s_load stream) feeds both queries' math. No clamp (see prep).
// ---------------------------------------------------------------------------
__global__ __launch_bounds__(256) void sknn_main(
    const float* __restrict__ rss, const float* __restrict__ sigma,
    const f4* __restrict__ Pg, float* __restrict__ acc)
{
    const int tid = threadIdx.x;
    const int q0  = blockIdx.x * (256 * QPT) + tid;   // and q1 = q0 + 256
    const int q1  = q0 + 256;
    const float sg = sigma[0];
    const float g  = 1.4426950408889634f / (2.0f * sg * sg);

    const float x00 = rss[q0*5+0], x01 = rss[q0*5+1], x02 = rss[q0*5+2];
    const float x03 = rss[q0*5+3], x04 = rss[q0*5+4];
    const float x10 = rss[q1*5+0], x11 = rss[q1*5+1], x12 = rss[q1*5+2];
    const float x13 = rss[q1*5+3], x14 = rss[q1*5+4];
    const float aq0 = -g*(x00*x00 + x01*x01 + x02*x02 + x03*x03 + x04*x04);
    const float aq1 = -g*(x10*x10 + x11*x11 + x12*x12 + x13*x13 + x14*x14);

    const f2 x00v={x00,x00}, x01v={x01,x01}, x02v={x02,x02}, x03v={x03,x03}, x04v={x04,x04};
    const f2 x10v={x10,x10}, x11v={x11,x11}, x12v={x12,x12}, x13v={x13,x13}, x14v={x14,x14};
    const f2 aq0v={aq0,aq0}, aq1v={aq1,aq1};
    const f2 zero={0.f,0.f};

    const f4* __restrict__ Pp = Pg + 4 * (size_t)(blockIdx.y * PAIRS_PER_CHUNK);

    f2 ss0=zero, a00=zero, a01=zero;   // query q0: sum, loc0, loc1
    f2 ss1=zero, a10=zero, a11=zero;   // query q1
    #pragma unroll 4
    for (int p = 0; p < PAIRS_PER_CHUNK; ++p) {
        const f4 pA = Pp[4*p+0];   // wave-uniform -> scalar loads
        const f4 pB = Pp[4*p+1];
        const f4 pC = Pp[4*p+2];
        const f4 pD = Pp[4*p+3];

        f2 t0 = pC.zw + aq0v;
        t0 = fma2(x00v, pA.xy, t0);
        t0 = fma2(x01v, pA.zw, t0);
        t0 = fma2(x02v, pB.xy, t0);
        t0 = fma2(x03v, pB.zw, t0);
        t0 = fma2(x04v, pC.xy, t0);
        f2 t1 = pC.zw + aq1v;
        t1 = fma2(x10v, pA.xy, t1);
        t1 = fma2(x11v, pA.zw, t1);
        t1 = fma2(x12v, pB.xy, t1);
        t1 = fma2(x13v, pB.zw, t1);
        t1 = fma2(x14v, pC.xy, t1);

        f2 s0; s0.x = EXP2F(t0.x); s0.y = EXP2F(t0.y);
        f2 s1; s1.x = EXP2F(t1.x); s1.y = EXP2F(t1.y);

        ss0 += s0;
        a00 = fma2(s0, pD.xy, a00);
        a01 = fma2(s0, pD.zw, a01);
        ss1 += s1;
        a10 = fma2(s1, pD.xy, a10);
        a11 = fma2(s1, pD.zw, a11);
    }

    atomicAdd(&acc[q0],          ss0.x + ss0.y);
    atomicAdd(&acc[QTOT + q0],   a00.x + a00.y);
    atomicAdd(&acc[2*QTOT + q0], a01.x + a01.y);
    atomicAdd(&acc[q1],          ss1.x + ss1.y);
    atomicAdd(&acc[QTOT + q1],   a10.x + a10.y);
    atomicAdd(&acc[2*QTOT + q1], a11.x + a11.y);
}

__global__ __launch_bounds__(256) void sknn_fin(
    const float* __restrict__ acc, float* __restrict__ out)
{
    const int q = blockIdx.x * 256 + threadIdx.x;
    if (q < QTOT) {
        const float inv = 1.0f / acc[q];
        out[q*2+0] = acc[QTOT + q]   * inv;
        out[q*2+1] = acc[2*QTOT + q] * inv;
    }
}

extern "C" void kernel_launch(void* const* d_in, const int* in_sizes, int n_in,
                              void* d_out, int out_size, void* d_ws, size_t ws_size,
                              hipStream_t stream) {
    const float* rss   = (const float*)d_in[0];
    const float* Radio = (const float*)d_in[1];
    const float* Loc   = (const float*)d_in[2];
    const float* sigma = (const float*)d_in[3];
    float* out = (float*)d_out;

    // ws layout: [Pg: NPAIRS*4*f4 ~= 1.62 MB][acc: 48 KB]
    f4*    Pg  = (f4*)d_ws;
    float* acc = (float*)((char*)d_ws + (size_t)NPAIRS * 4 * sizeof(f4));

    sknn_prep<<<(NPAIRS + 255) / 256, dim3(256), 0, stream>>>(Radio, Loc, sigma, Pg, acc);
    dim3 grid(QBLOCKS, NCHUNKS);
    sknn_main<<<grid, dim3(256), 0, stream>>>(rss, sigma, Pg, acc);
    sknn_fin<<<QTOT / 256, dim3(256), 0, stream>>>(acc, out);
}

// Round 5
// 112.246 us; speedup vs baseline: 1.1389x; 1.0249x over previous
//
#include <hip/hip_runtime.h>
#include <hip/hip_bf16.h>
#include <math.h>

// Q=4096 queries, N=50000 refs, D=5, L=2
// t[q][n] = 2g*(x.r) - g|x|^2 - g|r|^2,  g = log2e/(2 sigma^2);  s = 2^t
// Computed as a K=8 augmented dot product on the MFMA pipe with split-bf16:
//   A_aug[q] = (x0..x4, -g|x|^2, 1, 0)       (hi+lo bf16 split)
//   B_aug[n] = (2g*r0..2g*r4, 1, -g|r|^2, 0) (hi+lo bf16 split)
// One mfma_f32_16x16x32_bf16 per 16x16 tile with K-layout
//   A32 = [Ah(8) | Ah(8) | Al(8) | 0(8)],  B32 = [Bh(8) | Bl(8) | Bh(8) | 0(8)]
// => dot = Ah.Bh + Ah.Bl + Al.Bh  (error ~2^-17 relative — fp32-grade).
#define QTOT   4096
#define NTOT   50000
#define NTILES 3125            // 50000 / 16 exactly
#define NS     32              // n-splits (waves per q-group)
#define QG     64              // q-groups of 64 queries (4 tiles) each
#define ACCN   (3 * QTOT)

// ws layout (bytes)
#define BOFF   0u                          // B table: [ntile][2][16][8 ushort] = 512 B/tile
#define BSIZE  (3125u * 512u)              // 1,600,000
#define AOFF   (BOFF + BSIZE)              // A table: [q][2][8 ushort] = 32 B/q
#define ASIZE  (4096u * 32u)               // 131,072
#define ZOFF   (AOFF + ASIZE)              // 256 B zero block
#define ACCOFF (ZOFF + 256u)               // 3*Q fp32 accumulators

typedef unsigned short ushort_t;
typedef short  s16x8 __attribute__((ext_vector_type(8)));   // 8 bf16 (4 VGPRs)
typedef float  f32x4 __attribute__((ext_vector_type(4)));
typedef float  f2    __attribute__((ext_vector_type(2)));

#if __has_builtin(__builtin_amdgcn_exp2f)
#define EXP2F(x) __builtin_amdgcn_exp2f(x)
#else
#define EXP2F(x) exp2f(x)
#endif

static __device__ __forceinline__ f2 fma2(f2 a, f2 b, f2 c) {
#if __has_builtin(__builtin_elementwise_fma)
    return __builtin_elementwise_fma(a, b, c);
#else
    f2 r; r.x = fmaf(a.x, b.x, c.x); r.y = fmaf(a.y, b.y, c.y); return r;
#endif
}

static __device__ __forceinline__ void bsplit(float f, ushort_t& h, ushort_t& l) {
    __hip_bfloat16 hb = __float2bfloat16(f);          // RNE
    float hf = __bfloat162float(hb);
    __hip_bfloat16 lb = __float2bfloat16(f - hf);
    h = *reinterpret_cast<ushort_t*>(&hb);
    l = *reinterpret_cast<ushort_t*>(&lb);
}

// ---------------------------------------------------------------------------
// Prep: build split-bf16 A/B tables, zero block, and zero the accumulators.
// ---------------------------------------------------------------------------
__global__ __launch_bounds__(256) void sknn_prep(
    const float* __restrict__ rss, const float* __restrict__ Radio,
    const float* __restrict__ sigma, char* __restrict__ ws)
{
    const int p = blockIdx.x * 256 + threadIdx.x;
    const float sg = sigma[0];
    const float g  = 1.4426950408889634f / (2.0f * sg * sg);
    const float g2 = 2.0f * g;

    if (p < NTOT) {                       // B entry for ref n = p
        float b[8];
        float rr = 0.f;
        #pragma unroll
        for (int d = 0; d < 5; ++d) { float r = Radio[p * 5 + d]; b[d] = g2 * r; rr += r * r; }
        b[5] = 1.0f; b[6] = -g * rr; b[7] = 0.0f;
        union { ushort_t u[8]; f32x4 v; } hi, lo;
        #pragma unroll
        for (int k = 0; k < 8; ++k) bsplit(b[k], hi.u[k], lo.u[k]);
        const int nt = p >> 4, nsub = p & 15;
        *(f32x4*)(ws + BOFF + (unsigned)nt * 512u + (unsigned)nsub * 16u)        = hi.v;
        *(f32x4*)(ws + BOFF + (unsigned)nt * 512u + 256u + (unsigned)nsub * 16u) = lo.v;
    }
    if (p < QTOT) {                       // A entry for query q = p
        float a[8];
        float xx = 0.f;
        #pragma unroll
        for (int d = 0; d < 5; ++d) { float x = rss[p * 5 + d]; a[d] = x; xx += x * x; }
        a[5] = -g * xx; a[6] = 1.0f; a[7] = 0.0f;
        union { ushort_t u[8]; f32x4 v; } hi, lo;
        #pragma unroll
        for (int k = 0; k < 8; ++k) bsplit(a[k], hi.u[k], lo.u[k]);
        *(f32x4*)(ws + AOFF + (unsigned)p * 32u)       = hi.v;
        *(f32x4*)(ws + AOFF + (unsigned)p * 32u + 16u) = lo.v;
    }
    if (p < 16)  *(f32x4*)(ws + ZOFF + (unsigned)p * 16u) = (f32x4){0.f, 0.f, 0.f, 0.f};
    if (p < ACCN) ((float*)(ws + ACCOFF))[p] = 0.0f;
}

// ---------------------------------------------------------------------------
// Main: 2048 waves; wave = (qg, ns). Wave holds 4 A-frags (64 queries),
// sweeps n-tiles nt = ns, ns+32, ... For each n-tile: 1 coalesced 16B/lane
// B-frag load, 4 MFMAs (t-tiles), 16 exp2, fp32 weighted accumulation.
// C/D layout: col = lane&15 (n_sub), row = (lane>>4)*4 + reg (q_sub).
// ---------------------------------------------------------------------------
__global__ __launch_bounds__(256) void sknn_main(
    const char* __restrict__ tbl, const float* __restrict__ Loc,
    float* __restrict__ acc)
{
    const int tid  = threadIdx.x;
    const int lane = tid & 63;
    const int wid  = (blockIdx.x * 256 + tid) >> 6;   // 0..2047
    const int qg   = wid >> 5;                        // 0..63
    const int ns   = wid & (NS - 1);                  // 0..31
    const int qbase = qg * 64;
    const int j  = lane & 15;                         // m/n sub-index
    const int qd = lane >> 4;                         // K-quadrant / row group

    // A-fragments (once per wave). Quadrants: 0,1 -> Ah; 2 -> Al; 3 -> 0.
    const unsigned abase = (qd == 3) ? (ZOFF + (unsigned)j * 16u)
        : (AOFF + (unsigned)(qbase + j) * 32u + (qd == 2 ? 16u : 0u));
    const unsigned astep = (qd == 3) ? 0u : 512u;     // 16 queries * 32 B
    const s16x8 a0 = *(const s16x8*)(tbl + abase);
    const s16x8 a1 = *(const s16x8*)(tbl + abase + astep);
    const s16x8 a2 = *(const s16x8*)(tbl + abase + 2u * astep);
    const s16x8 a3 = *(const s16x8*)(tbl + abase + 3u * astep);

    // B-fragment stream. Quadrants: 0 -> Bh; 1 -> Bl; 2 -> Bh; 3 -> 0.
    unsigned bofs = (qd == 3) ? (ZOFF + (unsigned)j * 16u)
        : (BOFF + (unsigned)ns * 512u + (qd == 1 ? 256u : 0u) + (unsigned)j * 16u);
    const unsigned bstep = (qd == 3) ? 0u : (512u * NS);

    // Loc stream: lane's column n = nt*16 + j  (8 B per lane per tile)
    unsigned lofs = (unsigned)(ns * 16 + j) * 8u;
    const char* locb = (const char*)Loc;

    float sm[16];  f2 o[16];
    #pragma unroll
    for (int k = 0; k < 16; ++k) { sm[k] = 0.f; o[k] = (f2){0.f, 0.f}; }
    const f32x4 zz = {0.f, 0.f, 0.f, 0.f};

    s16x8 bcur = *(const s16x8*)(tbl + bofs);
    f2    lcur = *(const f2*)(locb + lofs);

    for (int nt = ns; nt < NTILES; nt += NS) {
        const bool has = (nt + NS) < NTILES;
        const unsigned bn = bofs + (has ? bstep : 0u);
        const unsigned ln = lofs + (has ? (unsigned)(NS * 16 * 8) : 0u);
        const s16x8 bnx = *(const s16x8*)(tbl + bn);   // prefetch next
        const f2    lnx = *(const f2*)(locb + ln);

        f32x4 t[4];
        t[0] = __builtin_amdgcn_mfma_f32_16x16x32_bf16(a0, bcur, zz, 0, 0, 0);
        t[1] = __builtin_amdgcn_mfma_f32_16x16x32_bf16(a1, bcur, zz, 0, 0, 0);
        t[2] = __builtin_amdgcn_mfma_f32_16x16x32_bf16(a2, bcur, zz, 0, 0, 0);
        t[3] = __builtin_amdgcn_mfma_f32_16x16x32_bf16(a3, bcur, zz, 0, 0, 0);

        #pragma unroll
        for (int qt = 0; qt < 4; ++qt) {
            #pragma unroll
            for (int i = 0; i < 4; ++i) {
                const float s = EXP2F(t[qt][i]);
                sm[qt * 4 + i] += s;
                o[qt * 4 + i] = fma2((f2){s, s}, lcur, o[qt * 4 + i]);
            }
        }
        bcur = bnx; lcur = lnx; bofs = bn; lofs = ln;
    }

    // Butterfly-reduce across the 16 lanes of each row group (xor 1,2,4,8).
    #pragma unroll
    for (int m = 1; m <= 8; m <<= 1) {
        #pragma unroll
        for (int k = 0; k < 16; ++k) {
            sm[k]  += __shfl_xor(sm[k],  m, 64);
            o[k].x += __shfl_xor(o[k].x, m, 64);
            o[k].y += __shfl_xor(o[k].y, m, 64);
        }
    }

    // One lane per (qt,i) combo per group writes its row's 3 partials.
    #pragma unroll
    for (int qt = 0; qt < 4; ++qt) {
        #pragma unroll
        for (int i = 0; i < 4; ++i) {
            if (j == qt * 4 + i) {
                const int q = qbase + qt * 16 + qd * 4 + i;
                atomicAdd(&acc[q],            sm[qt * 4 + i]);
                atomicAdd(&acc[QTOT + q],     o[qt * 4 + i].x);
                atomicAdd(&acc[2 * QTOT + q], o[qt * 4 + i].y);
            }
        }
    }
}

__global__ __launch_bounds__(256) void sknn_fin(
    const float* __restrict__ acc, float* __restrict__ out)
{
    const int q = blockIdx.x * 256 + threadIdx.x;
    if (q < QTOT) {
        const float inv = 1.0f / acc[q];
        out[q * 2 + 0] = acc[QTOT + q]     * inv;
        out[q * 2 + 1] = acc[2 * QTOT + q] * inv;
    }
}

extern "C" void kernel_launch(void* const* d_in, const int* in_sizes, int n_in,
                              void* d_out, int out_size, void* d_ws, size_t ws_size,
                              hipStream_t stream) {
    const float* rss   = (const float*)d_in[0];
    const float* Radio = (const float*)d_in[1];
    const float* Loc   = (const float*)d_in[2];
    const float* sigma = (const float*)d_in[3];
    float* out = (float*)d_out;
    char*  ws  = (char*)d_ws;
    float* acc = (float*)(ws + ACCOFF);

    sknn_prep<<<(NTOT + 255) / 256, dim3(256), 0, stream>>>(rss, Radio, sigma, ws);
    sknn_main<<<512, dim3(256), 0, stream>>>(ws, Loc, acc);   // 2048 waves
    sknn_fin<<<QTOT / 256, dim3(256), 0, stream>>>(acc, out);
}